// Round 6
// baseline (71.383 us; speedup 1.0000x reference)
//
#include <hip/hip_runtime.h>

// Problem geometry (from reference setup_inputs):
//   signal1: [N=16, F1=288, B=64, A=64] f32
//   signal2: [N=16, F2=480, B=64, A=64] f32
//   mixing_matrix: [768, 768] one-hot permutation (deterministic merge of
//   channel blocks by l; derived analytically below, validated by harness)
//   out: [N=16, C=768, B=64, A=64] f32,  out[n,d] = combined[n, perm(d)]
//
// Derived permutation (from build_mixing_matrix with RS_IN1/RS_IN2):
//   d in [  0,128) -> s1 channel d        (l=0 block + s1 l=1 block)
//   d in [128,224) -> s2 channel d-128    (s2 l=1 block)
//   d in [224,384) -> s1 channel d-96     (s1 l=2 block)
//   d in [384,768) -> s2 channel d-288    (s2 l=2 and l=3 blocks, contiguous)
#define NBATCH 16
#define F1 288
#define F2 480
#define CTOT 768
#define SLAB 4096   // B*A floats per channel slab

typedef float f32x4 __attribute__((ext_vector_type(4)));  // native vec for nontemporal builtins

// Gather-copy. One block per TWO (n,d) slabs: 256 threads x 8 float4.
// All 8 loads issued before any store -> deeper VMEM pipeline per wave.
__global__ __launch_bounds__(256) void gather_copy_kernel(
        const float* __restrict__ s1, const float* __restrict__ s2,
        float* __restrict__ out) {
    const int t = threadIdx.x;

    const f32x4* src[2];
    f32x4* dst[2];
#pragma unroll
    for (int h = 0; h < 2; ++h) {
        const int nd = blockIdx.x * 2 + h;   // n*CTOT + d
        const int n  = nd / CTOT;
        const int d  = nd - n * CTOT;

        // Analytic perm: pick source stream + channel with 3 compares.
        const float* srcbase;
        int c; size_t fdim;
        if (d < 128)      { srcbase = s1; c = d;       fdim = F1; }
        else if (d < 224) { srcbase = s2; c = d - 128; fdim = F2; }
        else if (d < 384) { srcbase = s1; c = d - 96;  fdim = F1; }
        else              { srcbase = s2; c = d - 288; fdim = F2; }

        src[h] = (const f32x4*)(srcbase + ((size_t)n * fdim + c) * SLAB);
        dst[h] = (f32x4*)(out + (size_t)nd * SLAB);
    }

    // Stage: issue all 8 loads, then all 8 stores.
    f32x4 v[2][4];
#pragma unroll
    for (int h = 0; h < 2; ++h)
#pragma unroll
        for (int k = 0; k < 4; ++k)
            v[h][k] = __builtin_nontemporal_load(&src[h][t + 256 * k]);

#pragma unroll
    for (int h = 0; h < 2; ++h)
#pragma unroll
        for (int k = 0; k < 4; ++k)
            __builtin_nontemporal_store(v[h][k], &dst[h][t + 256 * k]);
}

extern "C" void kernel_launch(void* const* d_in, const int* in_sizes, int n_in,
                              void* d_out, int out_size, void* d_ws, size_t ws_size,
                              hipStream_t stream) {
    const float* s1 = (const float*)d_in[0];
    const float* s2 = (const float*)d_in[1];
    float* out = (float*)d_out;

    gather_copy_kernel<<<NBATCH * CTOT / 2, 256, 0, stream>>>(s1, s2, out);
}